// Round 2
// baseline (5534.946 us; speedup 1.0000x reference)
//
#include <hip/hip_runtime.h>
#include <math.h>

#define HH     128
#define GHN    9
#define GWN    9
#define BATCH  4096
#define NCELL  81
#define MSAMP  8
#define THREADS 512
#define NBLK   (BATCH / MSAMP)   // 512 blocks -> 2 per CU, 16 waves/CU
#define KS     512               // comb row stride (m-major): [8][512] floats
#define EPSF   1e-5f

__device__ __forceinline__ float rcp_fast(float x) { return __builtin_amdgcn_rcpf(x); }
__device__ __forceinline__ float rsq_fast(float x) { return __builtin_amdgcn_rsqf(x); }
__device__ __forceinline__ float sigm(float x)     { return rcp_fast(1.f + __expf(-x)); }
__device__ __forceinline__ float tanh_fast(float x) {
    float ax = fabsf(x);
    float t  = __expf(-2.f * ax);
    float r  = (1.f - t) * rcp_fast(1.f + t);
    return (x < 0.f) ? -r : r;
}
__device__ __forceinline__ float f4c(const float4& v, int c) {
    switch (c) { case 0: return v.x; case 1: return v.y; case 2: return v.z; default: return v.w; }
}

// ---------------------------------------------------------------------------
// Weight transpose, coalesced READS + scattered writes (writes don't stall):
//   whT/wcT : [81][96][128] float4   dst[k][kb][r] = Wh[k][r][4kb..4kb+3]
//   whhT    : [81][32][512] float4   dst[k][kb][o] = W_hh[k][o][4kb..4kb+3]
// ---------------------------------------------------------------------------
__global__ __launch_bounds__(256)
void k_transpose(const float* __restrict__ Wh, const float* __restrict__ Wc,
                 const float* __restrict__ Whh,
                 float* __restrict__ whT, float* __restrict__ wcT,
                 float* __restrict__ whhT)
{
    const int n1 = 81 * 128 * 96;   // float4 count for Wh/Wc (src order k,r,kb)
    const int n2 = 81 * 512 * 32;   // float4 count for Whh (src order k,o,kb)
    int gid    = blockIdx.x * blockDim.x + threadIdx.x;
    int stride = gridDim.x * blockDim.x;
    for (int s = gid; s < n1; s += stride) {
        int kb = s % 96;
        int rt = s / 96;            // k*128 + r
        int r  = rt & 127;
        int k  = rt >> 7;
        int d  = (k * 96 + kb) * 128 + r;
        ((float4*)whT)[d] = ((const float4*)Wh)[s];
        ((float4*)wcT)[d] = ((const float4*)Wc)[s];
    }
    for (int s = gid; s < n2; s += stride) {
        int kb = s & 31;
        int ot = s >> 5;            // k*512 + o
        int o  = ot & 511;
        int k  = ot >> 9;
        int d  = (k * 32 + kb) * 512 + o;
        ((float4*)whhT)[d] = ((const float4*)Whh)[s];
    }
}

// ---------------------------------------------------------------------------
// Persistent lattice kernel: 512 blocks x 8 samples, 512 threads (8 waves).
// comb LDS layout, m-major: comb[m][kk], kk bands:
//   [  0..127] left / h_new      [128..255] up      [256..383] prev
//   [384..511] ph (post-LN)  -- pc for combC
// All GEMM reads are wave-uniform broadcasts; all writes lane-consecutive.
// Barriers: B1 after build, B3 after LN writeback, + 1 per row start (j==0).
// ---------------------------------------------------------------------------
__global__ __launch_bounds__(THREADS, 4)
void k_lattice(const float* __restrict__ x, const float* __restrict__ h_ext,
               const float* __restrict__ c_ext, const float* __restrict__ h_g0,
               const float* __restrict__ c_g0,
               const float* __restrict__ whT, const float* __restrict__ wcT,
               const float* __restrict__ whhT,
               const float* __restrict__ bh, const float* __restrict__ bc,
               const float* __restrict__ lnh_g, const float* __restrict__ lnh_b,
               const float* __restrict__ lnc_g, const float* __restrict__ lnc_b,
               const float* __restrict__ W_ih, const float* __restrict__ b_ih,
               const float* __restrict__ b_hh,
               float* __restrict__ hrowB, float* __restrict__ crowB,
               float* __restrict__ zout)
{
    __shared__ float combH[MSAMP * KS];
    __shared__ float combC[MSAMP * KS];
    __shared__ float xs[MSAMP * NCELL];

    const int t    = threadIdx.x;
    const int base = blockIdx.x * MSAMP;

    // preload x for all cells of this block's samples
    for (int idx = t; idx < MSAMP * NCELL; idx += THREADS) {
        int m = idx / NCELL;
        int c = idx - m * NCELL;
        xs[idx] = x[(size_t)(base + m) * NCELL + c];
    }

    // roles (wave id = t>>6)
    const int rs  = t & 63;        // preLN: rows rs, rs+64; build: h-part
    const int mg  = t >> 6;        // 0..7 = sample (preLN + build)
    const int q   = t & 127;       // gates/pointwise feature
    const int m0b = (t >> 7) * 2;  // gates/pointwise: samples m0b, m0b+1

    for (int i = 0; i < GHN; ++i) {
      for (int j = 0; j < GWN; ++j) {
        const int k = i * GWN + j;

        // row start overwrites the left band [0..127] -> fence vs previous
        // cell's pointwise writes to the same band.
        if (j == 0) __syncthreads();

        // ------------------ build phase ------------------
        float* cbHm = &combH[mg * KS];
        float* cbCm = &combC[mg * KS];
        if (j == 0) {
            if (i == 0) {
                const float* he = h_ext + (size_t)(base + mg) * HH;
                const float* ce = c_ext + (size_t)(base + mg) * HH;
                cbHm[rs]      = he[rs];      cbHm[rs + 64] = he[rs + 64];
                cbCm[rs]      = ce[rs];      cbCm[rs + 64] = ce[rs + 64];
            } else {
                cbHm[rs] = 0.f; cbHm[rs + 64] = 0.f;
                cbCm[rs] = 0.f; cbCm[rs + 64] = 0.f;
            }
        }
        if (i == 0) {
            cbHm[128 + rs] = 0.f; cbHm[128 + rs + 64] = 0.f;
            cbCm[128 + rs] = 0.f; cbCm[128 + rs + 64] = 0.f;
        } else {
            const float* hr = hrowB + ((size_t)(base + mg) * GWN + j) * HH;
            const float* cr = crowB + ((size_t)(base + mg) * GWN + j) * HH;
            cbHm[128 + rs] = hr[rs]; cbHm[128 + rs + 64] = hr[rs + 64];
            cbCm[128 + rs] = cr[rs]; cbCm[128 + rs + 64] = cr[rs + 64];
        }
        {
            const float* hp = h_g0 + ((size_t)k * BATCH + base + mg) * HH;
            const float* cp = c_g0 + ((size_t)k * BATCH + base + mg) * HH;
            cbHm[256 + rs] = hp[rs]; cbHm[256 + rs + 64] = hp[rs + 64];
            cbCm[256 + rs] = cp[rs]; cbCm[256 + rs + 64] = cp[rs + 64];
        }
        __syncthreads();   // B1: comb [0..383] built

        // ------------------ pre-LN matmuls (H and C) ------------------
        float aH0 = bh[k * HH + rs], aH1 = bh[k * HH + rs + 64];
        float aC0 = bc[k * HH + rs], aC1 = bc[k * HH + rs + 64];
        {
            const float4* wh4 = (const float4*)whT + (size_t)k * 96 * 128;
            const float4* wc4 = (const float4*)wcT + (size_t)k * 96 * 128;
            #pragma unroll 2
            for (int kb = 0; kb < 96; ++kb) {
                const float4 w0 = wh4[kb * 128 + rs];
                const float4 w1 = wh4[kb * 128 + rs + 64];
                const float4 u0 = wc4[kb * 128 + rs];
                const float4 u1 = wc4[kb * 128 + rs + 64];
                const float4 ch = *(const float4*)&cbHm[4 * kb];   // broadcast
                const float4 cc = *(const float4*)&cbCm[4 * kb];   // broadcast
                #pragma unroll
                for (int c = 0; c < 4; ++c) {
                    const float hv = f4c(ch, c), cv = f4c(cc, c);
                    aH0 += f4c(w0, c) * hv;
                    aH1 += f4c(w1, c) * hv;
                    aC0 += f4c(u0, c) * cv;
                    aC1 += f4c(u1, c) * cv;
                }
            }
        }

        // ------------------ LayerNorm + write ph/pc into band [384..511] ----
        {
            float sH = aH0 + aH1, qH = aH0 * aH0 + aH1 * aH1;
            float sC = aC0 + aC1, qC = aC0 * aC0 + aC1 * aC1;
            #pragma unroll
            for (int d = 1; d < 64; d <<= 1) {
                sH += __shfl_xor(sH, d); qH += __shfl_xor(qH, d);
                sC += __shfl_xor(sC, d); qC += __shfl_xor(qC, d);
            }
            const float muH = sH * (1.f / HH);
            const float rH  = rsq_fast(qH * (1.f / HH) - muH * muH + EPSF);
            const float muC = sC * (1.f / HH);
            const float rC  = rsq_fast(qC * (1.f / HH) - muC * muC + EPSF);
            cbHm[384 + rs]      = (aH0 - muH) * rH * lnh_g[k * HH + rs]      + lnh_b[k * HH + rs];
            cbHm[384 + rs + 64] = (aH1 - muH) * rH * lnh_g[k * HH + rs + 64] + lnh_b[k * HH + rs + 64];
            cbCm[384 + rs]      = (aC0 - muC) * rC * lnc_g[k * HH + rs]      + lnc_b[k * HH + rs];
            cbCm[384 + rs + 64] = (aC1 - muC) * rC * lnc_g[k * HH + rs + 64] + lnc_b[k * HH + rs + 64];
        }
        __syncthreads();   // B3: ph/pc visible

        // ------------------ gates GEMM ------------------
        float g00, g01, g10, g11, g20, g21, g30, g31;
        {
            const float xr0 = xs[m0b * NCELL + k];
            const float xr1 = xs[(m0b + 1) * NCELL + k];
            {
                const float w0 = W_ih[k * 512 + q];
                const float w1 = W_ih[k * 512 + q + 128];
                const float w2 = W_ih[k * 512 + q + 256];
                const float w3 = W_ih[k * 512 + q + 384];
                const float b0 = b_ih[k * 512 + q]       + b_hh[k * 512 + q];
                const float b1 = b_ih[k * 512 + q + 128] + b_hh[k * 512 + q + 128];
                const float b2 = b_ih[k * 512 + q + 256] + b_hh[k * 512 + q + 256];
                const float b3 = b_ih[k * 512 + q + 384] + b_hh[k * 512 + q + 384];
                g00 = b0 + w0 * xr0; g01 = b0 + w0 * xr1;
                g10 = b1 + w1 * xr0; g11 = b1 + w1 * xr1;
                g20 = b2 + w2 * xr0; g21 = b2 + w2 * xr1;
                g30 = b3 + w3 * xr0; g31 = b3 + w3 * xr1;
            }
            const float4* whh4 = (const float4*)whhT + (size_t)k * 32 * 512;
            const float* p0 = &combH[m0b * KS + 384];
            const float* p1 = &combH[(m0b + 1) * KS + 384];
            #pragma unroll 2
            for (int kb = 0; kb < 32; ++kb) {
                const float4 wv0 = whh4[kb * 512 + q];
                const float4 wv1 = whh4[kb * 512 + q + 128];
                const float4 wv2 = whh4[kb * 512 + q + 256];
                const float4 wv3 = whh4[kb * 512 + q + 384];
                const float4 pa = *(const float4*)&p0[4 * kb];   // broadcast
                const float4 pb = *(const float4*)&p1[4 * kb];   // broadcast
                #pragma unroll
                for (int c = 0; c < 4; ++c) {
                    const float va = f4c(pa, c), vb = f4c(pb, c);
                    g00 += f4c(wv0, c) * va; g01 += f4c(wv0, c) * vb;
                    g10 += f4c(wv1, c) * va; g11 += f4c(wv1, c) * vb;
                    g20 += f4c(wv2, c) * va; g21 += f4c(wv2, c) * vb;
                    g30 += f4c(wv3, c) * va; g31 += f4c(wv3, c) * vb;
                }
            }
        }

        // ------------------ LSTM pointwise + writeback (no barrier needed) --
        {
            const float pc0 = combC[m0b * KS + 384 + q];
            const float pc1 = combC[(m0b + 1) * KS + 384 + q];
            const float cn0 = sigm(g10) * pc0 + sigm(g00) * tanh_fast(g20);
            const float cn1 = sigm(g11) * pc1 + sigm(g01) * tanh_fast(g21);
            const float hn0 = sigm(g30) * tanh_fast(cn0);
            const float hn1 = sigm(g31) * tanh_fast(cn1);
            combH[m0b * KS + q]       = hn0;
            combH[(m0b + 1) * KS + q] = hn1;
            combC[m0b * KS + q]       = cn0;
            combC[(m0b + 1) * KS + q] = cn1;
            const int b0i = base + m0b, b1i = base + m0b + 1;
            if (k == NCELL - 1) {
                zout[(size_t)b0i * 256 + q]       = hn0 + h_ext[(size_t)b0i * HH + q];
                zout[(size_t)b1i * 256 + q]       = hn1 + h_ext[(size_t)b1i * HH + q];
                zout[(size_t)b0i * 256 + 128 + q] = cn0 + c_ext[(size_t)b0i * HH + q];
                zout[(size_t)b1i * 256 + 128 + q] = cn1 + c_ext[(size_t)b1i * HH + q];
            } else {
                hrowB[((size_t)b0i * GWN + j) * HH + q] = hn0;
                hrowB[((size_t)b1i * GWN + j) * HH + q] = hn1;
                crowB[((size_t)b0i * GWN + j) * HH + q] = cn0;
                crowB[((size_t)b1i * GWN + j) * HH + q] = cn1;
            }
        }
        // next build writes bands [128..383] (disjoint); B1 fences visibility.
      }
    }
}

// ---------------------------------------------------------------------------
// fc1: y1 = z @ fc1_W^T + b  [4096,256], fused column sum/sumsq atomics
// ---------------------------------------------------------------------------
__global__ __launch_bounds__(256)
void k_fc1(const float* __restrict__ z, const float* __restrict__ W,
           const float* __restrict__ bias, float* __restrict__ y1,
           float* __restrict__ s1, float* __restrict__ q1)
{
    __shared__ float at[256 * 16];  // [k][row]
    const int t   = threadIdx.x;
    const int row = t & 15;
    const int cg  = t >> 4;
    const int rb  = blockIdx.x * 16;
    {
        const float* zr = z + (size_t)(rb + row) * 256 + cg * 16;
        #pragma unroll
        for (int v = 0; v < 4; ++v) {
            const float4 zz = *(const float4*)(zr + v * 4);
            const int kk = cg * 16 + v * 4;
            at[(kk + 0) * 16 + row] = zz.x;
            at[(kk + 1) * 16 + row] = zz.y;
            at[(kk + 2) * 16 + row] = zz.z;
            at[(kk + 3) * 16 + row] = zz.w;
        }
    }
    __syncthreads();
    const int c0 = cg * 16;
    float acc[16];
    #pragma unroll
    for (int c = 0; c < 16; ++c) acc[c] = bias[c0 + c];
    for (int kb = 0; kb < 64; ++kb) {
        const float a0 = at[(4 * kb + 0) * 16 + row];
        const float a1 = at[(4 * kb + 1) * 16 + row];
        const float a2 = at[(4 * kb + 2) * 16 + row];
        const float a3 = at[(4 * kb + 3) * 16 + row];
        #pragma unroll
        for (int c = 0; c < 16; ++c) {
            const float4 wv = *(const float4*)&W[(size_t)(c0 + c) * 256 + 4 * kb];
            acc[c] += a0 * wv.x + a1 * wv.y + a2 * wv.z + a3 * wv.w;
        }
    }
    {
        float* yr = y1 + (size_t)(rb + row) * 256 + c0;
        #pragma unroll
        for (int v = 0; v < 4; ++v)
            *(float4*)(yr + v * 4) = make_float4(acc[4*v], acc[4*v+1], acc[4*v+2], acc[4*v+3]);
    }
    #pragma unroll
    for (int c = 0; c < 16; ++c) {
        float s = acc[c], sq = acc[c] * acc[c];
        s += __shfl_xor(s, 1); sq += __shfl_xor(sq, 1);
        s += __shfl_xor(s, 2); sq += __shfl_xor(sq, 2);
        s += __shfl_xor(s, 4); sq += __shfl_xor(sq, 4);
        s += __shfl_xor(s, 8); sq += __shfl_xor(sq, 8);
        if (row == 0) { atomicAdd(&s1[c0 + c], s); atomicAdd(&q1[c0 + c], sq); }
    }
}

// ---------------------------------------------------------------------------
// fc2: y2 = relu(bn1(y1)) @ fc2_W^T + b  [4096,128], fused stats
// ---------------------------------------------------------------------------
__global__ __launch_bounds__(256)
void k_fc2(const float* __restrict__ y1, const float* __restrict__ W,
           const float* __restrict__ bias,
           const float* __restrict__ s1, const float* __restrict__ q1,
           const float* __restrict__ g1, const float* __restrict__ b1,
           float* __restrict__ y2, float* __restrict__ s2, float* __restrict__ q2)
{
    __shared__ float at[256 * 16];
    __shared__ float scale[256], shift[256];
    const int t = threadIdx.x;
    {
        const float mu  = s1[t] * (1.f / BATCH);
        const float var = q1[t] * (1.f / BATCH) - mu * mu;
        const float sc  = g1[t] * rsq_fast(var + EPSF);
        scale[t] = sc;
        shift[t] = b1[t] - mu * sc;
    }
    __syncthreads();
    const int row = t & 15;
    const int cg  = t >> 4;
    const int rb  = blockIdx.x * 16;
    {
        const float* yr = y1 + (size_t)(rb + row) * 256 + cg * 16;
        #pragma unroll
        for (int v = 0; v < 4; ++v) {
            const float4 zz = *(const float4*)(yr + v * 4);
            const int kk = cg * 16 + v * 4;
            at[(kk + 0) * 16 + row] = fmaxf(zz.x * scale[kk + 0] + shift[kk + 0], 0.f);
            at[(kk + 1) * 16 + row] = fmaxf(zz.y * scale[kk + 1] + shift[kk + 1], 0.f);
            at[(kk + 2) * 16 + row] = fmaxf(zz.z * scale[kk + 2] + shift[kk + 2], 0.f);
            at[(kk + 3) * 16 + row] = fmaxf(zz.w * scale[kk + 3] + shift[kk + 3], 0.f);
        }
    }
    __syncthreads();
    const int c0 = cg * 8;
    float acc[8];
    #pragma unroll
    for (int c = 0; c < 8; ++c) acc[c] = bias[c0 + c];
    for (int kb = 0; kb < 64; ++kb) {
        const float a0 = at[(4 * kb + 0) * 16 + row];
        const float a1 = at[(4 * kb + 1) * 16 + row];
        const float a2 = at[(4 * kb + 2) * 16 + row];
        const float a3 = at[(4 * kb + 3) * 16 + row];
        #pragma unroll
        for (int c = 0; c < 8; ++c) {
            const float4 wv = *(const float4*)&W[(size_t)(c0 + c) * 256 + 4 * kb];
            acc[c] += a0 * wv.x + a1 * wv.y + a2 * wv.z + a3 * wv.w;
        }
    }
    {
        float* yr = y2 + (size_t)(rb + row) * 128 + c0;
        *(float4*)(yr)     = make_float4(acc[0], acc[1], acc[2], acc[3]);
        *(float4*)(yr + 4) = make_float4(acc[4], acc[5], acc[6], acc[7]);
    }
    #pragma unroll
    for (int c = 0; c < 8; ++c) {
        float s = acc[c], sq = acc[c] * acc[c];
        s += __shfl_xor(s, 1); sq += __shfl_xor(sq, 1);
        s += __shfl_xor(s, 2); sq += __shfl_xor(sq, 2);
        s += __shfl_xor(s, 4); sq += __shfl_xor(sq, 4);
        s += __shfl_xor(s, 8); sq += __shfl_xor(sq, 8);
        if (row == 0) { atomicAdd(&s2[c0 + c], s); atomicAdd(&q2[c0 + c], sq); }
    }
}

// ---------------------------------------------------------------------------
// fc3: y3 = relu(bn2(y2)) @ fc3_W^T + b  [4096,1], fused scalar stats
// ---------------------------------------------------------------------------
__global__ __launch_bounds__(256)
void k_fc3(const float* __restrict__ y2, const float* __restrict__ W3,
           const float* __restrict__ b3,
           const float* __restrict__ s2, const float* __restrict__ q2,
           const float* __restrict__ g2, const float* __restrict__ b2,
           float* __restrict__ y3, float* __restrict__ s3, float* __restrict__ q3)
{
    __shared__ float scale[128], shift[128], w3s[128];
    const int t = threadIdx.x;
    if (t < 128) {
        const float mu  = s2[t] * (1.f / BATCH);
        const float var = q2[t] * (1.f / BATCH) - mu * mu;
        const float sc  = g2[t] * rsq_fast(var + EPSF);
        scale[t] = sc;
        shift[t] = b2[t] - mu * sc;
        w3s[t]   = W3[t];
    }
    __syncthreads();
    const int r = blockIdx.x * 256 + t;
    float acc = b3[0];
    const float* yr = y2 + (size_t)r * 128;
    for (int kb = 0; kb < 32; ++kb) {
        const float4 v = *(const float4*)(yr + 4 * kb);
        const int kk = 4 * kb;
        acc += fmaxf(v.x * scale[kk + 0] + shift[kk + 0], 0.f) * w3s[kk + 0];
        acc += fmaxf(v.y * scale[kk + 1] + shift[kk + 1], 0.f) * w3s[kk + 1];
        acc += fmaxf(v.z * scale[kk + 2] + shift[kk + 2], 0.f) * w3s[kk + 2];
        acc += fmaxf(v.w * scale[kk + 3] + shift[kk + 3], 0.f) * w3s[kk + 3];
    }
    y3[r] = acc;
    float s = acc, sq = acc * acc;
    #pragma unroll
    for (int d = 1; d < 64; d <<= 1) { s += __shfl_xor(s, d); sq += __shfl_xor(sq, d); }
    if ((t & 63) == 0) { atomicAdd(&s3[0], s); atomicAdd(&q3[0], sq); }
}

// ---------------------------------------------------------------------------
// out = sigmoid(bn_out(y3))
// ---------------------------------------------------------------------------
__global__ __launch_bounds__(256)
void k_out(const float* __restrict__ y3,
           const float* __restrict__ s3, const float* __restrict__ q3,
           const float* __restrict__ g, const float* __restrict__ b,
           float* __restrict__ out)
{
    const int r = blockIdx.x * 256 + threadIdx.x;
    const float mu  = s3[0] * (1.f / BATCH);
    const float var = q3[0] * (1.f / BATCH) - mu * mu;
    const float sc  = g[0] * rsq_fast(var + EPSF);
    out[r] = sigm((y3[r] - mu) * sc + b[0]);
}

// ---------------------------------------------------------------------------
extern "C" void kernel_launch(void* const* d_in, const int* in_sizes, int n_in,
                              void* d_out, int out_size, void* d_ws, size_t ws_size,
                              hipStream_t stream)
{
    const float* x     = (const float*)d_in[0];
    const float* h_ext = (const float*)d_in[1];
    const float* c_ext = (const float*)d_in[2];
    const float* h_g0  = (const float*)d_in[3];
    const float* c_g0  = (const float*)d_in[4];
    const float* Wh    = (const float*)d_in[5];
    const float* bh    = (const float*)d_in[6];
    const float* Wc    = (const float*)d_in[7];
    const float* bc    = (const float*)d_in[8];
    const float* lnh_g = (const float*)d_in[9];
    const float* lnh_b = (const float*)d_in[10];
    const float* lnc_g = (const float*)d_in[11];
    const float* lnc_b = (const float*)d_in[12];
    const float* W_ih  = (const float*)d_in[13];
    const float* b_ih  = (const float*)d_in[14];
    const float* W_hh  = (const float*)d_in[15];
    const float* b_hh  = (const float*)d_in[16];
    const float* fc1_W = (const float*)d_in[17];
    const float* fc1_b = (const float*)d_in[18];
    const float* bn1_g = (const float*)d_in[19];
    const float* bn1_b = (const float*)d_in[20];
    const float* fc2_W = (const float*)d_in[21];
    const float* fc2_b = (const float*)d_in[22];
    const float* bn2_g = (const float*)d_in[23];
    const float* bn2_b = (const float*)d_in[24];
    const float* fc3_W = (const float*)d_in[25];
    const float* fc3_b = (const float*)d_in[26];
    const float* bno_g = (const float*)d_in[27];
    const float* bno_b = (const float*)d_in[28];

    float* ws   = (float*)d_ws;
    float* whT  = ws;                        // 81*96*128*4 = 3,981,312 floats
    float* wcT  = whT  + 3981312;
    float* whhT = wcT  + 3981312;            // 81*32*512*4 = 5,308,416
    float* hrow = whhT + 5308416;            // 4096*9*128  = 4,718,592
    float* crow = hrow + 4718592;
    float* z    = crow + 4718592;            // 4096*256 = 1,048,576
    float* y1   = z    + 1048576;            // 1,048,576
    float* y2   = y1   + 1048576;            // 524,288
    float* y3   = y2   + 524288;             // 4,096
    float* st   = y3   + 4096;               // 770 stats floats
    float* s1 = st;        float* q1 = s1 + 256;
    float* s2 = q1 + 256;  float* q2 = s2 + 128;
    float* s3 = q2 + 128;  float* q3 = s3 + 1;

    hipMemsetAsync(st, 0, 770 * sizeof(float), stream);
    hipLaunchKernelGGL(k_transpose, dim3(1024), dim3(256), 0, stream,
                       Wh, Wc, W_hh, whT, wcT, whhT);
    hipLaunchKernelGGL(k_lattice, dim3(NBLK), dim3(THREADS), 0, stream,
                       x, h_ext, c_ext, h_g0, c_g0, whT, wcT, whhT, bh, bc,
                       lnh_g, lnh_b, lnc_g, lnc_b, W_ih, b_ih, b_hh, hrow, crow, z);
    hipLaunchKernelGGL(k_fc1, dim3(256), dim3(256), 0, stream, z, fc1_W, fc1_b, y1, s1, q1);
    hipLaunchKernelGGL(k_fc2, dim3(256), dim3(256), 0, stream,
                       y1, fc2_W, fc2_b, s1, q1, bn1_g, bn1_b, y2, s2, q2);
    hipLaunchKernelGGL(k_fc3, dim3(16), dim3(256), 0, stream,
                       y2, fc3_W, fc3_b, s2, q2, bn2_g, bn2_b, y3, s3, q3);
    hipLaunchKernelGGL(k_out, dim3(16), dim3(256), 0, stream,
                       y3, s3, q3, bno_g, bno_b, (float*)d_out);
}

// Round 3
// 3021.133 us; speedup vs baseline: 1.8321x; 1.8321x over previous
//
#include <hip/hip_runtime.h>
#include <math.h>

#define HH      128
#define GHN     9
#define GWN     9
#define BATCH   4096
#define NCELL   81
#define MSAMP   16
#define THREADS 512
#define NBLK    (BATCH / MSAMP)   // 256 blocks -> 1 per CU, 8 waves
#define EPSF    1e-5f

__device__ __forceinline__ float rcp_fast(float x) { return __builtin_amdgcn_rcpf(x); }
__device__ __forceinline__ float rsq_fast(float x) { return __builtin_amdgcn_rsqf(x); }
__device__ __forceinline__ float sigm(float x)     { return rcp_fast(1.f + __expf(-x)); }
__device__ __forceinline__ float tanh_fast(float x) {
    float ax = fabsf(x);
    float t  = __expf(-2.f * ax);
    float r  = (1.f - t) * rcp_fast(1.f + t);
    return (x < 0.f) ? -r : r;
}

// ---------------------------------------------------------------------------
// Weight transpose (coalesced reads, scattered writes):
//   whT/wcT : [81][96][128] float4   dst[k][kb][r] = Wh[k][r][4kb..4kb+3]
//   whhT    : [81][32][512] float4   dst[k][kb][o] = W_hh[k][o][4kb..4kb+3]
// ---------------------------------------------------------------------------
__global__ __launch_bounds__(256)
void k_transpose(const float* __restrict__ Wh, const float* __restrict__ Wc,
                 const float* __restrict__ Whh,
                 float* __restrict__ whT, float* __restrict__ wcT,
                 float* __restrict__ whhT)
{
    const int n1 = 81 * 128 * 96;
    const int n2 = 81 * 512 * 32;
    int gid    = blockIdx.x * blockDim.x + threadIdx.x;
    int stride = gridDim.x * blockDim.x;
    for (int s = gid; s < n1; s += stride) {
        int kb = s % 96;
        int rt = s / 96;
        int r  = rt & 127;
        int k  = rt >> 7;
        int d  = (k * 96 + kb) * 128 + r;
        ((float4*)whT)[d] = ((const float4*)Wh)[s];
        ((float4*)wcT)[d] = ((const float4*)Wc)[s];
    }
    for (int s = gid; s < n2; s += stride) {
        int kb = s & 31;
        int ot = s >> 5;
        int o  = ot & 511;
        int k  = ot >> 9;
        int d  = (k * 32 + kb) * 512 + o;
        ((float4*)whhT)[d] = ((const float4*)Whh)[s];
    }
}

// ---------------------------------------------------------------------------
// Lattice kernel: 256 blocks x 16 samples, 512 threads (8 waves).
// comb[m][kk] (m-major, 512 floats/sample): [0..127] left/h_new,
// [128..255] up, [256..383] prev, [384..511] ph (pc for combC).
// pg (32KB) = preLN partial scratch (24KB) / gates scratch (32KB), time-shared.
// preLN waves: (hc, kb-half, sample-half), 2 rows x 8 samples accums.
// gates waves: (output-quarter, sample-half), 2 outputs x 8 samples accums.
// ---------------------------------------------------------------------------
__global__ __launch_bounds__(THREADS, 2)
void k_lattice(const float* __restrict__ x, const float* __restrict__ h_ext,
               const float* __restrict__ c_ext, const float* __restrict__ h_g0,
               const float* __restrict__ c_g0,
               const float* __restrict__ whT, const float* __restrict__ wcT,
               const float* __restrict__ whhT,
               const float* __restrict__ bh, const float* __restrict__ bc,
               const float* __restrict__ lnh_g, const float* __restrict__ lnh_b,
               const float* __restrict__ lnc_g, const float* __restrict__ lnc_b,
               const float* __restrict__ W_ih, const float* __restrict__ b_ih,
               const float* __restrict__ b_hh,
               float* __restrict__ hrowB, float* __restrict__ crowB,
               float* __restrict__ zout)
{
    __shared__ float combH[MSAMP * 512];   // 32KB
    __shared__ float combC[MSAMP * 512];   // 32KB
    __shared__ float pg[MSAMP * 512];      // 32KB: pscr [4][128][12] / gscr [16][512]
    __shared__ float xs[MSAMP * NCELL];    // 5KB

    const int t    = threadIdx.x;
    const int base = blockIdx.x * MSAMP;
    const int rs   = t & 63;       // lane
    const int w    = t >> 6;       // wave 0..7

    // preLN roles
    const int hc  = w & 1;         // 0:H 1:C
    const int kh  = (w >> 1) & 1;  // kb half
    const int m0p = (w >> 2) * 8;  // sample half
    // gates roles
    const int oq  = w & 3;         // output quarter
    const int m0g = (w >> 2) * 8;
    const int o0  = oq * 64 + rs;  // [0,256)
    const int o1  = o0 + 256;      // [256,512)
    // build roles
    const int m_b = t >> 5;        // 0..15
    const int h4  = (t & 31) * 4;
    // pointwise roles
    const int q   = t & 127;
    const int m0w = (t >> 7) * 4;

    for (int idx = t; idx < MSAMP * NCELL; idx += THREADS) {
        int m = idx / NCELL;
        int c = idx - m * NCELL;
        xs[idx] = x[(size_t)(base + m) * NCELL + c];
    }
    const float4 z4 = make_float4(0.f, 0.f, 0.f, 0.f);

    for (int i = 0; i < GHN; ++i) {
      for (int j = 0; j < GWN; ++j) {
        const int k = i * GWN + j;

        // ---------------- build: bands up/prev (+left at j==0) ----------------
        {
            float* bH = &combH[m_b * 512];
            float* bC = &combC[m_b * 512];
            if (j == 0) {
                if (i == 0) {
                    *(float4*)&bH[h4] = *(const float4*)&h_ext[(size_t)(base + m_b) * HH + h4];
                    *(float4*)&bC[h4] = *(const float4*)&c_ext[(size_t)(base + m_b) * HH + h4];
                } else {
                    *(float4*)&bH[h4] = z4;
                    *(float4*)&bC[h4] = z4;
                }
            }
            if (i == 0) {
                *(float4*)&bH[128 + h4] = z4;
                *(float4*)&bC[128 + h4] = z4;
            } else {
                *(float4*)&bH[128 + h4] =
                    *(const float4*)&hrowB[((size_t)(base + m_b) * GWN + j) * HH + h4];
                *(float4*)&bC[128 + h4] =
                    *(const float4*)&crowB[((size_t)(base + m_b) * GWN + j) * HH + h4];
            }
            *(float4*)&bH[256 + h4] =
                *(const float4*)&h_g0[((size_t)k * BATCH + base + m_b) * HH + h4];
            *(float4*)&bC[256 + h4] =
                *(const float4*)&c_g0[((size_t)k * BATCH + base + m_b) * HH + h4];
        }
        __syncthreads();   // B1

        // ---------------- preLN GEMM: 2 rows x 8 samples per thread ----------
        float acc0[8], acc1[8];
        #pragma unroll
        for (int ms = 0; ms < 8; ++ms) { acc0[ms] = 0.f; acc1[ms] = 0.f; }
        {
            const float4* w4 = (const float4*)(hc ? wcT : whT) + (size_t)k * 96 * 128;
            const float*  cb = (hc ? combC : combH) + m0p * 512;
            const int kb0 = kh * 48;
            #pragma unroll 2
            for (int kb = kb0; kb < kb0 + 48; ++kb) {
                const float4 wv0 = w4[kb * 128 + rs];
                const float4 wv1 = w4[kb * 128 + rs + 64];
                const float* cbp = cb + 4 * kb;
                #pragma unroll
                for (int ms = 0; ms < 8; ++ms) {
                    const float4 cv = *(const float4*)(cbp + ms * 512);
                    acc0[ms] += wv0.x * cv.x + wv0.y * cv.y + wv0.z * cv.z + wv0.w * cv.w;
                    acc1[ms] += wv1.x * cv.x + wv1.y * cv.y + wv1.z * cv.z + wv1.w * cv.w;
                }
            }
        }
        // kb-upper waves publish partials: pscr[hc*2+sh][row][12]
        const int pb = ((w >> 1) & 1 ? 0 : 0, (hc * 2 + (w >> 2)) * 1536);
        if (kh == 1) {
            *(float4*)&pg[pb + rs * 12 + 0]        = make_float4(acc0[0], acc0[1], acc0[2], acc0[3]);
            *(float4*)&pg[pb + rs * 12 + 4]        = make_float4(acc0[4], acc0[5], acc0[6], acc0[7]);
            *(float4*)&pg[pb + (rs + 64) * 12 + 0] = make_float4(acc1[0], acc1[1], acc1[2], acc1[3]);
            *(float4*)&pg[pb + (rs + 64) * 12 + 4] = make_float4(acc1[4], acc1[5], acc1[6], acc1[7]);
        }
        __syncthreads();   // B2

        // ---------------- merge + LayerNorm (kb-lower waves) -----------------
        if (kh == 0) {
            const float4 pa0 = *(const float4*)&pg[pb + rs * 12 + 0];
            const float4 pa1 = *(const float4*)&pg[pb + rs * 12 + 4];
            const float4 pc0 = *(const float4*)&pg[pb + (rs + 64) * 12 + 0];
            const float4 pc1 = *(const float4*)&pg[pb + (rs + 64) * 12 + 4];
            const float* bsrc = hc ? bc : bh;
            const float bb0 = bsrc[k * HH + rs], bb1 = bsrc[k * HH + rs + 64];
            acc0[0] += pa0.x + bb0; acc0[1] += pa0.y + bb0;
            acc0[2] += pa0.z + bb0; acc0[3] += pa0.w + bb0;
            acc0[4] += pa1.x + bb0; acc0[5] += pa1.y + bb0;
            acc0[6] += pa1.z + bb0; acc0[7] += pa1.w + bb0;
            acc1[0] += pc0.x + bb1; acc1[1] += pc0.y + bb1;
            acc1[2] += pc0.z + bb1; acc1[3] += pc0.w + bb1;
            acc1[4] += pc1.x + bb1; acc1[5] += pc1.y + bb1;
            acc1[6] += pc1.z + bb1; acc1[7] += pc1.w + bb1;

            float ss[8], qq[8];
            #pragma unroll
            for (int ms = 0; ms < 8; ++ms) {
                ss[ms] = acc0[ms] + acc1[ms];
                qq[ms] = acc0[ms] * acc0[ms] + acc1[ms] * acc1[ms];
            }
            #pragma unroll
            for (int d = 1; d < 64; d <<= 1) {
                #pragma unroll
                for (int ms = 0; ms < 8; ++ms) {
                    ss[ms] += __shfl_xor(ss[ms], d);
                    qq[ms] += __shfl_xor(qq[ms], d);
                }
            }
            const float* gsrc = hc ? lnc_g : lnh_g;
            const float* esrc = hc ? lnc_b : lnh_b;
            const float g0 = gsrc[k * HH + rs], g1 = gsrc[k * HH + rs + 64];
            const float e0 = esrc[k * HH + rs], e1 = esrc[k * HH + rs + 64];
            float* cbw = (hc ? combC : combH) + m0p * 512 + 384;
            #pragma unroll
            for (int ms = 0; ms < 8; ++ms) {
                const float mu = ss[ms] * (1.f / HH);
                const float rstd = rsq_fast(qq[ms] * (1.f / HH) - mu * mu + EPSF);
                cbw[ms * 512 + rs]      = (acc0[ms] - mu) * rstd * g0 + e0;
                cbw[ms * 512 + rs + 64] = (acc1[ms] - mu) * rstd * g1 + e1;
            }
        }
        __syncthreads();   // B3

        // ---------------- gates GEMM: 2 outputs x 8 samples ------------------
        float ga0[8], ga1[8];
        {
            const float wih0 = W_ih[k * 512 + o0];
            const float wih1 = W_ih[k * 512 + o1];
            const float bg0  = b_ih[k * 512 + o0] + b_hh[k * 512 + o0];
            const float bg1  = b_ih[k * 512 + o1] + b_hh[k * 512 + o1];
            #pragma unroll
            for (int ms = 0; ms < 8; ++ms) {
                const float xv = xs[(m0g + ms) * NCELL + k];
                ga0[ms] = bg0 + wih0 * xv;
                ga1[ms] = bg1 + wih1 * xv;
            }
            const float4* whh4 = (const float4*)whhT + (size_t)k * 32 * 512;
            const float*  php  = &combH[m0g * 512 + 384];
            #pragma unroll 2
            for (int kb = 0; kb < 32; ++kb) {
                const float4 wv0 = whh4[kb * 512 + o0];
                const float4 wv1 = whh4[kb * 512 + o1];
                const float* pp = php + 4 * kb;
                #pragma unroll
                for (int ms = 0; ms < 8; ++ms) {
                    const float4 pv = *(const float4*)(pp + ms * 512);
                    ga0[ms] += wv0.x * pv.x + wv0.y * pv.y + wv0.z * pv.z + wv0.w * pv.w;
                    ga1[ms] += wv1.x * pv.x + wv1.y * pv.y + wv1.z * pv.z + wv1.w * pv.w;
                }
            }
            #pragma unroll
            for (int ms = 0; ms < 8; ++ms) {
                pg[(m0g + ms) * 512 + o0] = ga0[ms];
                pg[(m0g + ms) * 512 + o1] = ga1[ms];
            }
        }
        __syncthreads();   // B4

        // ---------------- LSTM pointwise: 4 samples per thread ---------------
        #pragma unroll
        for (int s = 0; s < 4; ++s) {
            const int ms = m0w + s;
            const float gi = pg[ms * 512 + q];
            const float gf = pg[ms * 512 + q + 128];
            const float gg = pg[ms * 512 + q + 256];
            const float go = pg[ms * 512 + q + 384];
            const float pc = combC[ms * 512 + 384 + q];
            const float cn = sigm(gf) * pc + sigm(gi) * tanh_fast(gg);
            const float hn = sigm(go) * tanh_fast(cn);
            const int b = base + ms;
            if (k == NCELL - 1) {
                zout[(size_t)b * 256 + q]       = hn + h_ext[(size_t)b * HH + q];
                zout[(size_t)b * 256 + 128 + q] = cn + c_ext[(size_t)b * HH + q];
            } else {
                if (j < GWN - 1) {           // left-input for (i, j+1)
                    combH[ms * 512 + q] = hn;
                    combC[ms * 512 + q] = cn;
                }
                if (i < GHN - 1) {           // up-input for (i+1, j)
                    hrowB[((size_t)b * GWN + j) * HH + q] = hn;
                    crowB[((size_t)b * GWN + j) * HH + q] = cn;
                }
            }
        }
        // no trailing barrier: next build writes bands 128..383 only (disjoint),
        // and at j==0 the band-0 writers are the build phase itself (pointwise
        // skipped band 0 at j==8). B1 fences visibility.
      }
    }
}

// ---------------------------------------------------------------------------
// fc1: y1 = z @ fc1_W^T + b  [4096,256], fused column sum/sumsq atomics
// ---------------------------------------------------------------------------
__global__ __launch_bounds__(256)
void k_fc1(const float* __restrict__ z, const float* __restrict__ W,
           const float* __restrict__ bias, float* __restrict__ y1,
           float* __restrict__ s1, float* __restrict__ q1)
{
    __shared__ float at[256 * 16];
    const int t   = threadIdx.x;
    const int row = t & 15;
    const int cg  = t >> 4;
    const int rb  = blockIdx.x * 16;
    {
        const float* zr = z + (size_t)(rb + row) * 256 + cg * 16;
        #pragma unroll
        for (int v = 0; v < 4; ++v) {
            const float4 zz = *(const float4*)(zr + v * 4);
            const int kk = cg * 16 + v * 4;
            at[(kk + 0) * 16 + row] = zz.x;
            at[(kk + 1) * 16 + row] = zz.y;
            at[(kk + 2) * 16 + row] = zz.z;
            at[(kk + 3) * 16 + row] = zz.w;
        }
    }
    __syncthreads();
    const int c0 = cg * 16;
    float acc[16];
    #pragma unroll
    for (int c = 0; c < 16; ++c) acc[c] = bias[c0 + c];
    for (int kb = 0; kb < 64; ++kb) {
        const float a0 = at[(4 * kb + 0) * 16 + row];
        const float a1 = at[(4 * kb + 1) * 16 + row];
        const float a2 = at[(4 * kb + 2) * 16 + row];
        const float a3 = at[(4 * kb + 3) * 16 + row];
        #pragma unroll
        for (int c = 0; c < 16; ++c) {
            const float4 wv = *(const float4*)&W[(size_t)(c0 + c) * 256 + 4 * kb];
            acc[c] += a0 * wv.x + a1 * wv.y + a2 * wv.z + a3 * wv.w;
        }
    }
    {
        float* yr = y1 + (size_t)(rb + row) * 256 + c0;
        #pragma unroll
        for (int v = 0; v < 4; ++v)
            *(float4*)(yr + v * 4) = make_float4(acc[4*v], acc[4*v+1], acc[4*v+2], acc[4*v+3]);
    }
    #pragma unroll
    for (int c = 0; c < 16; ++c) {
        float s = acc[c], sq = acc[c] * acc[c];
        s += __shfl_xor(s, 1); sq += __shfl_xor(sq, 1);
        s += __shfl_xor(s, 2); sq += __shfl_xor(sq, 2);
        s += __shfl_xor(s, 4); sq += __shfl_xor(sq, 4);
        s += __shfl_xor(s, 8); sq += __shfl_xor(sq, 8);
        if (row == 0) { atomicAdd(&s1[c0 + c], s); atomicAdd(&q1[c0 + c], sq); }
    }
}

// ---------------------------------------------------------------------------
// fc2: y2 = relu(bn1(y1)) @ fc2_W^T + b  [4096,128], fused stats
// ---------------------------------------------------------------------------
__global__ __launch_bounds__(256)
void k_fc2(const float* __restrict__ y1, const float* __restrict__ W,
           const float* __restrict__ bias,
           const float* __restrict__ s1, const float* __restrict__ q1,
           const float* __restrict__ g1, const float* __restrict__ b1,
           float* __restrict__ y2, float* __restrict__ s2, float* __restrict__ q2)
{
    __shared__ float at[256 * 16];
    __shared__ float scale[256], shift[256];
    const int t = threadIdx.x;
    {
        const float mu  = s1[t] * (1.f / BATCH);
        const float var = q1[t] * (1.f / BATCH) - mu * mu;
        const float sc  = g1[t] * rsq_fast(var + EPSF);
        scale[t] = sc;
        shift[t] = b1[t] - mu * sc;
    }
    __syncthreads();
    const int row = t & 15;
    const int cg  = t >> 4;
    const int rb  = blockIdx.x * 16;
    {
        const float* yr = y1 + (size_t)(rb + row) * 256 + cg * 16;
        #pragma unroll
        for (int v = 0; v < 4; ++v) {
            const float4 zz = *(const float4*)(yr + v * 4);
            const int kk = cg * 16 + v * 4;
            at[(kk + 0) * 16 + row] = fmaxf(zz.x * scale[kk + 0] + shift[kk + 0], 0.f);
            at[(kk + 1) * 16 + row] = fmaxf(zz.y * scale[kk + 1] + shift[kk + 1], 0.f);
            at[(kk + 2) * 16 + row] = fmaxf(zz.z * scale[kk + 2] + shift[kk + 2], 0.f);
            at[(kk + 3) * 16 + row] = fmaxf(zz.w * scale[kk + 3] + shift[kk + 3], 0.f);
        }
    }
    __syncthreads();
    const int c0 = cg * 8;
    float acc[8];
    #pragma unroll
    for (int c = 0; c < 8; ++c) acc[c] = bias[c0 + c];
    for (int kb = 0; kb < 64; ++kb) {
        const float a0 = at[(4 * kb + 0) * 16 + row];
        const float a1 = at[(4 * kb + 1) * 16 + row];
        const float a2 = at[(4 * kb + 2) * 16 + row];
        const float a3 = at[(4 * kb + 3) * 16 + row];
        #pragma unroll
        for (int c = 0; c < 8; ++c) {
            const float4 wv = *(const float4*)&W[(size_t)(c0 + c) * 256 + 4 * kb];
            acc[c] += a0 * wv.x + a1 * wv.y + a2 * wv.z + a3 * wv.w;
        }
    }
    {
        float* yr = y2 + (size_t)(rb + row) * 128 + c0;
        *(float4*)(yr)     = make_float4(acc[0], acc[1], acc[2], acc[3]);
        *(float4*)(yr + 4) = make_float4(acc[4], acc[5], acc[6], acc[7]);
    }
    #pragma unroll
    for (int c = 0; c < 8; ++c) {
        float s = acc[c], sq = acc[c] * acc[c];
        s += __shfl_xor(s, 1); sq += __shfl_xor(sq, 1);
        s += __shfl_xor(s, 2); sq += __shfl_xor(sq, 2);
        s += __shfl_xor(s, 4); sq += __shfl_xor(sq, 4);
        s += __shfl_xor(s, 8); sq += __shfl_xor(sq, 8);
        if (row == 0) { atomicAdd(&s2[c0 + c], s); atomicAdd(&q2[c0 + c], sq); }
    }
}

// ---------------------------------------------------------------------------
// fc3: y3 = relu(bn2(y2)) @ fc3_W^T + b  [4096,1], fused scalar stats
// ---------------------------------------------------------------------------
__global__ __launch_bounds__(256)
void k_fc3(const float* __restrict__ y2, const float* __restrict__ W3,
           const float* __restrict__ b3,
           const float* __restrict__ s2, const float* __restrict__ q2,
           const float* __restrict__ g2, const float* __restrict__ b2,
           float* __restrict__ y3, float* __restrict__ s3, float* __restrict__ q3)
{
    __shared__ float scale[128], shift[128], w3s[128];
    const int t = threadIdx.x;
    if (t < 128) {
        const float mu  = s2[t] * (1.f / BATCH);
        const float var = q2[t] * (1.f / BATCH) - mu * mu;
        const float sc  = g2[t] * rsq_fast(var + EPSF);
        scale[t] = sc;
        shift[t] = b2[t] - mu * sc;
        w3s[t]   = W3[t];
    }
    __syncthreads();
    const int r = blockIdx.x * 256 + t;
    float acc = b3[0];
    const float* yr = y2 + (size_t)r * 128;
    for (int kb = 0; kb < 32; ++kb) {
        const float4 v = *(const float4*)(yr + 4 * kb);
        const int kk = 4 * kb;
        acc += fmaxf(v.x * scale[kk + 0] + shift[kk + 0], 0.f) * w3s[kk + 0];
        acc += fmaxf(v.y * scale[kk + 1] + shift[kk + 1], 0.f) * w3s[kk + 1];
        acc += fmaxf(v.z * scale[kk + 2] + shift[kk + 2], 0.f) * w3s[kk + 2];
        acc += fmaxf(v.w * scale[kk + 3] + shift[kk + 3], 0.f) * w3s[kk + 3];
    }
    y3[r] = acc;
    float s = acc, sq = acc * acc;
    #pragma unroll
    for (int d = 1; d < 64; d <<= 1) { s += __shfl_xor(s, d); sq += __shfl_xor(sq, d); }
    if ((t & 63) == 0) { atomicAdd(&s3[0], s); atomicAdd(&q3[0], sq); }
}

// ---------------------------------------------------------------------------
// out = sigmoid(bn_out(y3))
// ---------------------------------------------------------------------------
__global__ __launch_bounds__(256)
void k_out(const float* __restrict__ y3,
           const float* __restrict__ s3, const float* __restrict__ q3,
           const float* __restrict__ g, const float* __restrict__ b,
           float* __restrict__ out)
{
    const int r = blockIdx.x * 256 + threadIdx.x;
    const float mu  = s3[0] * (1.f / BATCH);
    const float var = q3[0] * (1.f / BATCH) - mu * mu;
    const float sc  = g[0] * rsq_fast(var + EPSF);
    out[r] = sigm((y3[r] - mu) * sc + b[0]);
}

// ---------------------------------------------------------------------------
extern "C" void kernel_launch(void* const* d_in, const int* in_sizes, int n_in,
                              void* d_out, int out_size, void* d_ws, size_t ws_size,
                              hipStream_t stream)
{
    const float* x     = (const float*)d_in[0];
    const float* h_ext = (const float*)d_in[1];
    const float* c_ext = (const float*)d_in[2];
    const float* h_g0  = (const float*)d_in[3];
    const float* c_g0  = (const float*)d_in[4];
    const float* Wh    = (const float*)d_in[5];
    const float* bh    = (const float*)d_in[6];
    const float* Wc    = (const float*)d_in[7];
    const float* bc    = (const float*)d_in[8];
    const float* lnh_g = (const float*)d_in[9];
    const float* lnh_b = (const float*)d_in[10];
    const float* lnc_g = (const float*)d_in[11];
    const float* lnc_b = (const float*)d_in[12];
    const float* W_ih  = (const float*)d_in[13];
    const float* b_ih  = (const float*)d_in[14];
    const float* W_hh  = (const float*)d_in[15];
    const float* b_hh  = (const float*)d_in[16];
    const float* fc1_W = (const float*)d_in[17];
    const float* fc1_b = (const float*)d_in[18];
    const float* bn1_g = (const float*)d_in[19];
    const float* bn1_b = (const float*)d_in[20];
    const float* fc2_W = (const float*)d_in[21];
    const float* fc2_b = (const float*)d_in[22];
    const float* bn2_g = (const float*)d_in[23];
    const float* bn2_b = (const float*)d_in[24];
    const float* fc3_W = (const float*)d_in[25];
    const float* fc3_b = (const float*)d_in[26];
    const float* bno_g = (const float*)d_in[27];
    const float* bno_b = (const float*)d_in[28];

    float* ws   = (float*)d_ws;
    float* whT  = ws;
    float* wcT  = whT  + 3981312;
    float* whhT = wcT  + 3981312;
    float* hrow = whhT + 5308416;
    float* crow = hrow + 4718592;
    float* z    = crow + 4718592;
    float* y1   = z    + 1048576;
    float* y2   = y1   + 1048576;
    float* y3   = y2   + 524288;
    float* st   = y3   + 4096;
    float* s1 = st;        float* q1 = s1 + 256;
    float* s2 = q1 + 256;  float* q2 = s2 + 128;
    float* s3 = q2 + 128;  float* q3 = s3 + 1;

    hipMemsetAsync(st, 0, 770 * sizeof(float), stream);
    hipLaunchKernelGGL(k_transpose, dim3(1024), dim3(256), 0, stream,
                       Wh, Wc, W_hh, whT, wcT, whhT);
    hipLaunchKernelGGL(k_lattice, dim3(NBLK), dim3(THREADS), 0, stream,
                       x, h_ext, c_ext, h_g0, c_g0, whT, wcT, whhT, bh, bc,
                       lnh_g, lnh_b, lnc_g, lnc_b, W_ih, b_ih, b_hh, hrow, crow, z);
    hipLaunchKernelGGL(k_fc1, dim3(256), dim3(256), 0, stream, z, fc1_W, fc1_b, y1, s1, q1);
    hipLaunchKernelGGL(k_fc2, dim3(256), dim3(256), 0, stream,
                       y1, fc2_W, fc2_b, s1, q1, bn1_g, bn1_b, y2, s2, q2);
    hipLaunchKernelGGL(k_fc3, dim3(16), dim3(256), 0, stream,
                       y2, fc3_W, fc3_b, s2, q2, bn2_g, bn2_b, y3, s3, q3);
    hipLaunchKernelGGL(k_out, dim3(16), dim3(256), 0, stream,
                       y3, s3, q3, bno_g, bno_b, (float*)d_out);
}

// Round 5
// 1901.913 us; speedup vs baseline: 2.9102x; 1.5885x over previous
//
#include <hip/hip_runtime.h>
#include <math.h>

#define HH      128
#define GHN     9
#define GWN     9
#define BATCH   4096
#define NCELL   81
#define MSAMP   16
#define THREADS 512
#define NBLK    (BATCH / MSAMP)   // 256 blocks -> 1 per CU, 8 waves
#define EPSF    1e-5f

typedef __attribute__((ext_vector_type(8))) short  bf8;     // 8 bf16 (4 VGPRs)
typedef __attribute__((ext_vector_type(4))) short  short4v; // 8 bytes
typedef __attribute__((ext_vector_type(4))) float  f32x4;

#define MFMA(a, b, c) __builtin_amdgcn_mfma_f32_16x16x32_bf16(a, b, c, 0, 0, 0)

__device__ __forceinline__ float rcp_fast(float x) { return __builtin_amdgcn_rcpf(x); }
__device__ __forceinline__ float rsq_fast(float x) { return __builtin_amdgcn_rsqf(x); }
__device__ __forceinline__ float sigm(float x)     { return rcp_fast(1.f + __expf(-x)); }
__device__ __forceinline__ float tanh_fast(float x) {
    float ax = fabsf(x);
    float t  = __expf(-2.f * ax);
    float r  = (1.f - t) * rcp_fast(1.f + t);
    return (x < 0.f) ? -r : r;
}
__device__ __forceinline__ short f2bf(float f) {        // RNE fp32->bf16
    unsigned u = __float_as_uint(f);
    u = (u + 0x7FFFu + ((u >> 16) & 1u)) >> 16;
    return (short)u;
}
__device__ __forceinline__ float bf2f(short h) {
    return __uint_as_float(((unsigned)(unsigned short)h) << 16);
}
__device__ __forceinline__ void split_bf(float f, short& hi, short& lo) {
    hi = f2bf(f);
    lo = f2bf(f - bf2f(hi));
}
// write 4 consecutive k-elements (same 8-group) of sample m into frag arrays
__device__ __forceinline__ void store_frag4(short* hiA, short* loA, int idx, float4 v) {
    short4v h, l; short a, b;
    split_bf(v.x, a, b); h.x = a; l.x = b;
    split_bf(v.y, a, b); h.y = a; l.y = b;
    split_bf(v.z, a, b); h.z = a; l.z = b;
    split_bf(v.w, a, b); h.w = a; l.w = b;
    *(short4v*)&hiA[idx] = h;
    *(short4v*)&loA[idx] = l;
}
// frag slot for (k multiple of 4, sample m): A layout [kstep][lane=(kgrp<<4)|m][8]
__device__ __forceinline__ int frag4_idx(int k, int m) {
    return (k >> 5) * 512 + ((((k & 31) >> 3) << 4) | m) * 8 + (k & 7);
}

// ---------------------------------------------------------------------------
// Build bf16 hi/lo B-fragments for all weights.
//   whB/wcB : [81][8 ntile][12 kstep][64 lane][8]   elem = W[k][16t+(l&15)][32s+(l>>4)*8+e]
//   whhB    : [81][32 ntile][4 kstep][64 lane][8]
// grid: 81 * 24 blocks (4 Wh pairs + 4 Wc pairs + 16 Whh chunks), 256 thr.
// ---------------------------------------------------------------------------
__global__ __launch_bounds__(256)
void k_buildw(const float* __restrict__ Wh, const float* __restrict__ Wc,
              const float* __restrict__ Whh,
              short* __restrict__ whB_hi, short* __restrict__ whB_lo,
              short* __restrict__ wcB_hi, short* __restrict__ wcB_lo,
              short* __restrict__ whhB_hi, short* __restrict__ whhB_lo)
{
    __shared__ float lw[32 * 384];   // 48KB max
    const int u  = threadIdx.x;
    const int kc = blockIdx.x / 24;
    const int c  = blockIdx.x % 24;

    if (c < 8) {                       // Wh (c<4) / Wc pairs
        const int mat = c >> 2;
        const int p   = c & 3;
        const float* src = (mat ? Wc : Wh) + ((size_t)kc * 128 + 32 * p) * 384;
        #pragma unroll
        for (int it = 0; it < 12; ++it)
            ((float4*)lw)[it * 256 + u] = ((const float4*)src)[it * 256 + u];
        __syncthreads();
        short* Dhi = mat ? wcB_hi : whB_hi;
        short* Dlo = mat ? wcB_lo : whB_lo;
        #pragma unroll
        for (int it = 0; it < 6; ++it) {
            const int wd = it * 256 + u;        // 0..1535
            const int tt = wd / 768;
            const int rm = wd - tt * 768;
            const int s  = rm >> 6;
            const int l  = rm & 63;
            const int rl = tt * 16 + (l & 15);
            const int kk = s * 32 + (l >> 4) * 8;
            const float* pr = &lw[rl * 384 + kk];
            const float4 v0 = *(const float4*)pr;
            const float4 v1 = *(const float4*)(pr + 4);
            const size_t dst = (((size_t)kc * 8 + (2 * p + tt)) * 12 + s) * 512 + l * 8;
            short4v h, lo; short a, b;
            split_bf(v0.x, a, b); h.x = a; lo.x = b;
            split_bf(v0.y, a, b); h.y = a; lo.y = b;
            split_bf(v0.z, a, b); h.z = a; lo.z = b;
            split_bf(v0.w, a, b); h.w = a; lo.w = b;
            *(short4v*)&Dhi[dst]     = h;  *(short4v*)&Dlo[dst]     = lo;
            split_bf(v1.x, a, b); h.x = a; lo.x = b;
            split_bf(v1.y, a, b); h.y = a; lo.y = b;
            split_bf(v1.z, a, b); h.z = a; lo.z = b;
            split_bf(v1.w, a, b); h.w = a; lo.w = b;
            *(short4v*)&Dhi[dst + 4] = h;  *(short4v*)&Dlo[dst + 4] = lo;
        }
    } else {                           // Whh chunks
        const int cc = c - 8;
        const float* src = Whh + ((size_t)kc * 512 + 32 * cc) * 128;
        #pragma unroll
        for (int it = 0; it < 4; ++it)
            ((float4*)lw)[it * 256 + u] = ((const float4*)src)[it * 256 + u];
        __syncthreads();
        #pragma unroll
        for (int it = 0; it < 2; ++it) {
            const int wd = it * 256 + u;        // 0..511
            const int tt = wd >> 8;
            const int rm = wd & 255;
            const int s  = rm >> 6;
            const int l  = rm & 63;
            const int rl = tt * 16 + (l & 15);
            const int kk = s * 32 + (l >> 4) * 8;
            const float* pr = &lw[rl * 128 + kk];
            const float4 v0 = *(const float4*)pr;
            const float4 v1 = *(const float4*)(pr + 4);
            const size_t dst = (((size_t)kc * 32 + (2 * cc + tt)) * 4 + s) * 512 + l * 8;
            short4v h, lo; short a, b;
            split_bf(v0.x, a, b); h.x = a; lo.x = b;
            split_bf(v0.y, a, b); h.y = a; lo.y = b;
            split_bf(v0.z, a, b); h.z = a; lo.z = b;
            split_bf(v0.w, a, b); h.w = a; lo.w = b;
            *(short4v*)&whhB_hi[dst]     = h;  *(short4v*)&whhB_lo[dst]     = lo;
            split_bf(v1.x, a, b); h.x = a; lo.x = b;
            split_bf(v1.y, a, b); h.y = a; lo.y = b;
            split_bf(v1.z, a, b); h.z = a; lo.z = b;
            split_bf(v1.w, a, b); h.w = a; lo.w = b;
            *(short4v*)&whhB_hi[dst + 4] = h;  *(short4v*)&whhB_lo[dst + 4] = lo;
        }
    }
}

// ---------------------------------------------------------------------------
// MFMA lattice: 256 blocks x 16 samples, 512 threads (8 waves).
// Activations as A-fragments in LDS (bf16 hi/lo), ksteps 0-3 left, 4-7 up,
// 8-11 prev. preLN: waves = {H,C} x 4 tile-pairs. gates: wave w owns tiles
// {w, w+8, w+16, w+24} -> all 4 gates of q0=w*16+(lane&15) in-register.
// 4-pass split product: ah*bh + ah*bl + al*bh + al*bl (~fp32-exact).
// ---------------------------------------------------------------------------
__global__ __launch_bounds__(THREADS, 2)
void k_lattice(const float* __restrict__ x, const float* __restrict__ h_ext,
               const float* __restrict__ c_ext, const float* __restrict__ h_g0,
               const float* __restrict__ c_g0,
               const short* __restrict__ whB_hi, const short* __restrict__ whB_lo,
               const short* __restrict__ wcB_hi, const short* __restrict__ wcB_lo,
               const short* __restrict__ whhB_hi, const short* __restrict__ whhB_lo,
               const float* __restrict__ bh, const float* __restrict__ bc,
               const float* __restrict__ lnh_g, const float* __restrict__ lnh_b,
               const float* __restrict__ lnc_g, const float* __restrict__ lnc_b,
               const float* __restrict__ W_ih, const float* __restrict__ b_ih,
               const float* __restrict__ b_hh,
               float* __restrict__ hrowB, float* __restrict__ crowB,
               float* __restrict__ zout)
{
    __shared__ __align__(16) short sAH_hi[12 * 512], sAH_lo[12 * 512];
    __shared__ __align__(16) short sAC_hi[12 * 512], sAC_lo[12 * 512];   // 48KB
    __shared__ __align__(16) short sPh_hi[4 * 512],  sPh_lo[4 * 512];    // 8KB
    __shared__ float pcArr[16 * 132];                                    // 8.25KB
    __shared__ float part[2 * 4 * 16 * 2];                               // 1KB
    __shared__ float xsArr[16 * NCELL];                                  // 5.2KB

    const int t    = threadIdx.x;
    const int base = blockIdx.x * MSAMP;
    const int lane = t & 63;
    const int w    = t >> 6;         // wave 0..7
    const int cL   = lane & 15;      // MFMA col (feature)
    const int gL   = lane >> 4;      // sample group (D rows gL*4 + r)

    // preLN roles
    const int mat = w >> 2;          // 0=H 1=C
    const int p   = w & 3;           // tile pair
    // build roles
    const int m_b = t >> 5;          // 0..15 sample
    const int f4  = (t & 31) * 4;    // feature quad

    for (int idx = t; idx < MSAMP * NCELL; idx += THREADS) {
        const int m = idx / NCELL;
        const int cc = idx - m * NCELL;
        xsArr[idx] = x[(size_t)(base + m) * NCELL + cc];
    }
    const float4 z4 = make_float4(0.f, 0.f, 0.f, 0.f);

    for (int i = 0; i < GHN; ++i) {
      for (int j = 0; j < GWN; ++j) {
        const int k = i * GWN + j;

        // ---------------- build: up/prev bands (+left at j==0) ---------------
        {
            if (j == 0) {
                float4 hv = z4, cv = z4;
                if (i == 0) {
                    hv = *(const float4*)&h_ext[(size_t)(base + m_b) * HH + f4];
                    cv = *(const float4*)&c_ext[(size_t)(base + m_b) * HH + f4];
                }
                store_frag4(sAH_hi, sAH_lo, frag4_idx(f4, m_b), hv);
                store_frag4(sAC_hi, sAC_lo, frag4_idx(f4, m_b), cv);
            }
            float4 uh = z4, uc = z4;
            if (i > 0) {
                uh = *(const float4*)&hrowB[((size_t)(base + m_b) * GWN + j) * HH + f4];
                uc = *(const float4*)&crowB[((size_t)(base + m_b) * GWN + j) * HH + f4];
            }
            store_frag4(sAH_hi, sAH_lo, frag4_idx(128 + f4, m_b), uh);
            store_frag4(sAC_hi, sAC_lo, frag4_idx(128 + f4, m_b), uc);
            const float4 pv = *(const float4*)&h_g0[((size_t)k * BATCH + base + m_b) * HH + f4];
            const float4 qv = *(const float4*)&c_g0[((size_t)k * BATCH + base + m_b) * HH + f4];
            store_frag4(sAH_hi, sAH_lo, frag4_idx(256 + f4, m_b), pv);
            store_frag4(sAC_hi, sAC_lo, frag4_idx(256 + f4, m_b), qv);
        }
        __syncthreads();   // B1

        // ---------------- preLN MFMA: 2 N-tiles, 4-pass bf16 split -----------
        const int t0 = 2 * p, t1 = 2 * p + 1;
        const short* Ahi = mat ? sAC_hi : sAH_hi;
        const short* Alo = mat ? sAC_lo : sAH_lo;
        const short* Bhi = (mat ? wcB_hi : whB_hi) + (size_t)k * 49152;
        const short* Blo = (mat ? wcB_lo : whB_lo) + (size_t)k * 49152;
        f32x4 d0 = {0.f, 0.f, 0.f, 0.f}, d1 = {0.f, 0.f, 0.f, 0.f};
        #pragma unroll 4
        for (int ks = 0; ks < 12; ++ks) {
            const bf8 ah  = *(const bf8*)&Ahi[ks * 512 + lane * 8];
            const bf8 al  = *(const bf8*)&Alo[ks * 512 + lane * 8];
            const bf8 b0h = *(const bf8*)&Bhi[(t0 * 12 + ks) * 512 + lane * 8];
            const bf8 b0l = *(const bf8*)&Blo[(t0 * 12 + ks) * 512 + lane * 8];
            const bf8 b1h = *(const bf8*)&Bhi[(t1 * 12 + ks) * 512 + lane * 8];
            const bf8 b1l = *(const bf8*)&Blo[(t1 * 12 + ks) * 512 + lane * 8];
            d0 = MFMA(al, b0l, d0); d0 = MFMA(al, b0h, d0);
            d0 = MFMA(ah, b0l, d0); d0 = MFMA(ah, b0h, d0);
            d1 = MFMA(al, b1l, d1); d1 = MFMA(al, b1h, d1);
            d1 = MFMA(ah, b1l, d1); d1 = MFMA(ah, b1h, d1);
        }
        const int f0 = t0 * 16 + cL, f1 = t1 * 16 + cL;
        {
            const float* bias = mat ? bc : bh;
            const float bb0 = bias[k * HH + f0], bb1 = bias[k * HH + f1];
            d0 += bb0; d1 += bb1;
        }
        // ---------------- LN partials (within-wave feature reduce) -----------
        {
            float ps[4], pq[4];
            #pragma unroll
            for (int r = 0; r < 4; ++r) {
                ps[r] = d0[r] + d1[r];
                pq[r] = d0[r] * d0[r] + d1[r] * d1[r];
            }
            #pragma unroll
            for (int msk = 1; msk < 16; msk <<= 1) {
                #pragma unroll
                for (int r = 0; r < 4; ++r) {
                    ps[r] += __shfl_xor(ps[r], msk);
                    pq[r] += __shfl_xor(pq[r], msk);
                }
            }
            if (cL == 0) {
                #pragma unroll
                for (int r = 0; r < 4; ++r) {
                    part[((mat * 4 + p) * 16 + gL * 4 + r) * 2 + 0] = ps[r];
                    part[((mat * 4 + p) * 16 + gL * 4 + r) * 2 + 1] = pq[r];
                }
            }
        }
        __syncthreads();   // B2

        // ---------------- combine stats + normalize + emit ph/pc -------------
        {
            const float* lng = mat ? lnc_g : lnh_g;
            const float* lnb = mat ? lnc_b : lnh_b;
            const float g0 = lng[k * HH + f0], g1 = lng[k * HH + f1];
            const float e0 = lnb[k * HH + f0], e1 = lnb[k * HH + f1];
            #pragma unroll
            for (int r = 0; r < 4; ++r) {
                const int s = gL * 4 + r;
                float ts = 0.f, tq = 0.f;
                #pragma unroll
                for (int pp = 0; pp < 4; ++pp) {
                    ts += part[((mat * 4 + pp) * 16 + s) * 2 + 0];
                    tq += part[((mat * 4 + pp) * 16 + s) * 2 + 1];
                }
                const float mu = ts * (1.f / HH);
                const float rstd = rsq_fast(tq * (1.f / HH) - mu * mu + EPSF);
                const float v0 = (d0[r] - mu) * rstd * g0 + e0;
                const float v1 = (d1[r] - mu) * rstd * g1 + e1;
                if (mat == 0) {
                    const int e0i = (f0 >> 5) * 512 + ((((f0 & 31) >> 3) << 4) | s) * 8 + (f0 & 7);
                    const int e1i = (f1 >> 5) * 512 + ((((f1 & 31) >> 3) << 4) | s) * 8 + (f1 & 7);
                    short hi, lo;
                    split_bf(v0, hi, lo); sPh_hi[e0i] = hi; sPh_lo[e0i] = lo;
                    split_bf(v1, hi, lo); sPh_hi[e1i] = hi; sPh_lo[e1i] = lo;
                } else {
                    pcArr[s * 132 + f0] = v0;
                    pcArr[s * 132 + f1] = v1;
                }
            }
        }
        __syncthreads();   // B3

        // ---------------- gates MFMA: tiles w, w+8, w+16, w+24 ---------------
        f32x4 ga0 = {0.f,0.f,0.f,0.f}, ga1 = ga0, ga2 = ga0, ga3 = ga0;
        {
            const short* GBhi = whhB_hi + (size_t)k * 65536;
            const short* GBlo = whhB_lo + (size_t)k * 65536;
            #pragma unroll
            for (int ks = 0; ks < 4; ++ks) {
                const bf8 ah = *(const bf8*)&sPh_hi[ks * 512 + lane * 8];
                const bf8 al = *(const bf8*)&sPh_lo[ks * 512 + lane * 8];
                const bf8 bh0 = *(const bf8*)&GBhi[((w     ) * 4 + ks) * 512 + lane * 8];
                const bf8 bl0 = *(const bf8*)&GBlo[((w     ) * 4 + ks) * 512 + lane * 8];
                const bf8 bh1 = *(const bf8*)&GBhi[((w +  8) * 4 + ks) * 512 + lane * 8];
                const bf8 bl1 = *(const bf8*)&GBlo[((w +  8) * 4 + ks) * 512 + lane * 8];
                const bf8 bh2 = *(const bf8*)&GBhi[((w + 16) * 4 + ks) * 512 + lane * 8];
                const bf8 bl2 = *(const bf8*)&GBlo[((w + 16) * 4 + ks) * 512 + lane * 8];
                const bf8 bh3 = *(const bf8*)&GBhi[((w + 24) * 4 + ks) * 512 + lane * 8];
                const bf8 bl3 = *(const bf8*)&GBlo[((w + 24) * 4 + ks) * 512 + lane * 8];
                ga0 = MFMA(al, bl0, ga0); ga0 = MFMA(al, bh0, ga0);
                ga0 = MFMA(ah, bl0, ga0); ga0 = MFMA(ah, bh0, ga0);
                ga1 = MFMA(al, bl1, ga1); ga1 = MFMA(al, bh1, ga1);
                ga1 = MFMA(ah, bl1, ga1); ga1 = MFMA(ah, bh1, ga1);
                ga2 = MFMA(al, bl2, ga2); ga2 = MFMA(al, bh2, ga2);
                ga2 = MFMA(ah, bl2, ga2); ga2 = MFMA(ah, bh2, ga2);
                ga3 = MFMA(al, bl3, ga3); ga3 = MFMA(al, bh3, ga3);
                ga3 = MFMA(ah, bl3, ga3); ga3 = MFMA(ah, bh3, ga3);
            }
        }
        // ---------------- bias + x + LSTM pointwise (in-register) ------------
        {
            const int q0 = w * 16 + cL;
            const float wi0 = W_ih[k * 512 + q0      ];
            const float wi1 = W_ih[k * 512 + q0 + 128];
            const float wi2 = W_ih[k * 512 + q0 + 256];
            const float wi3 = W_ih[k * 512 + q0 + 384];
            const float bs0 = b_ih[k * 512 + q0      ] + b_hh[k * 512 + q0      ];
            const float bs1 = b_ih[k * 512 + q0 + 128] + b_hh[k * 512 + q0 + 128];
            const float bs2 = b_ih[k * 512 + q0 + 256] + b_hh[k * 512 + q0 + 256];
            const float bs3 = b_ih[k * 512 + q0 + 384] + b_hh[k * 512 + q0 + 384];
            #pragma unroll
            for (int r = 0; r < 4; ++r) {
                const int s = gL * 4 + r;
                const int b = base + s;
                const float xv = xsArr[s * NCELL + k];
                const float gi_ = ga0[r] + bs0 + wi0 * xv;
                const float gf_ = ga1[r] + bs1 + wi1 * xv;
                const float gg_ = ga2[r] + bs2 + wi2 * xv;
                const float go_ = ga3[r] + bs3 + wi3 * xv;
                const float pcv = pcArr[s * 132 + q0];
                const float cn = sigm(gf_) * pcv + sigm(gi_) * tanh_fast(gg_);
                const float hn = sigm(go_) * tanh_fast(cn);
                if (k == NCELL - 1) {
                    zout[(size_t)b * 256 + q0]       = hn + h_ext[(size_t)b * HH + q0];
                    zout[(size_t)b * 256 + 128 + q0] = cn + c_ext[(size_t)b * HH + q0];
                } else {
                    if (j < GWN - 1) {
                        const int ei = (q0 >> 5) * 512 + ((((q0 & 31) >> 3) << 4) | s) * 8 + (q0 & 7);
                        short hi, lo;
                        split_bf(hn, hi, lo); sAH_hi[ei] = hi; sAH_lo[ei] = lo;
                        split_bf(cn, hi, lo); sAC_hi[ei] = hi; sAC_lo[ei] = lo;
                    }
                    if (i < GHN - 1) {
                        hrowB[((size_t)b * GWN + j) * HH + q0] = hn;
                        crowB[((size_t)b * GWN + j) * HH + q0] = cn;
                    }
                }
            }
        }
        // next B1 fences left-frag/pc visibility for the following cell
      }
    }
}

// ---------------------------------------------------------------------------
// fc1: y1 = z @ fc1_W^T + b  [4096,256], fused column sum/sumsq atomics
// ---------------------------------------------------------------------------
__global__ __launch_bounds__(256)
void k_fc1(const float* __restrict__ z, const float* __restrict__ W,
           const float* __restrict__ bias, float* __restrict__ y1,
           float* __restrict__ s1, float* __restrict__ q1)
{
    __shared__ float at[256 * 16];
    const int t   = threadIdx.x;
    const int row = t & 15;
    const int cg  = t >> 4;
    const int rb  = blockIdx.x * 16;
    {
        const float* zr = z + (size_t)(rb + row) * 256 + cg * 16;
        #pragma unroll
        for (int v = 0; v < 4; ++v) {
            const float4 zz = *(const float4*)(zr + v * 4);
            const int kk = cg * 16 + v * 4;
            at[(kk + 0) * 16 + row] = zz.x;
            at[(kk + 1) * 16 + row] = zz.y;
            at[(kk + 2) * 16 + row] = zz.z;
            at[(kk + 3) * 16 + row] = zz.w;
        }
    }
    __syncthreads();
    const int c0 = cg * 16;
    float acc[16];
    #pragma unroll
    for (int c = 0; c < 16; ++c) acc[c] = bias[c0 + c];
    for (int kb = 0; kb < 64; ++kb) {
        const float a0 = at[(4 * kb + 0) * 16 + row];
        const float a1 = at[(4 * kb + 1) * 16 + row];
        const float a2 = at[(4 * kb + 2) * 16 + row];
        const float a3 = at[(4 * kb + 3) * 16 + row];
        #pragma unroll
        for (int c = 0; c < 16; ++c) {
            const float4 wv = *(const float4*)&W[(size_t)(c0 + c) * 256 + 4 * kb];
            acc[c] += a0 * wv.x + a1 * wv.y + a2 * wv.z + a3 * wv.w;
        }
    }
    {
        float* yr = y1 + (size_t)(rb + row) * 256 + c0;
        #pragma unroll
        for (int v = 0; v < 4; ++v)
            *(float4*)(yr + v * 4) = make_float4(acc[4*v], acc[4*v+1], acc[4*v+2], acc[4*v+3]);
    }
    #pragma unroll
    for (int c = 0; c < 16; ++c) {
        float s = acc[c], sq = acc[c] * acc[c];
        s += __shfl_xor(s, 1); sq += __shfl_xor(sq, 1);
        s += __shfl_xor(s, 2); sq += __shfl_xor(sq, 2);
        s += __shfl_xor(s, 4); sq += __shfl_xor(sq, 4);
        s += __shfl_xor(s, 8); sq += __shfl_xor(sq, 8);
        if (row == 0) { atomicAdd(&s1[c0 + c], s); atomicAdd(&q1[c0 + c], sq); }
    }
}

// ---------------------------------------------------------------------------
// fc2: y2 = relu(bn1(y1)) @ fc2_W^T + b  [4096,128], fused stats
// ---------------------------------------------------------------------------
__global__ __launch_bounds__(256)
void k_fc2(const float* __restrict__ y1, const float* __restrict__ W,
           const float* __restrict__ bias,
           const float* __restrict__ s1, const float* __restrict__ q1,
           const float* __restrict__ g1, const float* __restrict__ b1,
           float* __restrict__ y2, float* __restrict__ s2, float* __restrict__ q2)
{
    __shared__ float at[256 * 16];
    __shared__ float scale[256], shift[256];
    const int t = threadIdx.x;
    {
        const float mu  = s1[t] * (1.f / BATCH);
        const float var = q1[t] * (1.f / BATCH) - mu * mu;
        const float sc  = g1[t] * rsq_fast(var + EPSF);
        scale[t] = sc;
        shift[t] = b1[t] - mu * sc;
    }
    __syncthreads();
    const int row = t & 15;
    const int cg  = t >> 4;
    const int rb  = blockIdx.x * 16;
    {
        const float* yr = y1 + (size_t)(rb + row) * 256 + cg * 16;
        #pragma unroll
        for (int v = 0; v < 4; ++v) {
            const float4 zz = *(const float4*)(yr + v * 4);
            const int kk = cg * 16 + v * 4;
            at[(kk + 0) * 16 + row] = fmaxf(zz.x * scale[kk + 0] + shift[kk + 0], 0.f);
            at[(kk + 1) * 16 + row] = fmaxf(zz.y * scale[kk + 1] + shift[kk + 1], 0.f);
            at[(kk + 2) * 16 + row] = fmaxf(zz.z * scale[kk + 2] + shift[kk + 2], 0.f);
            at[(kk + 3) * 16 + row] = fmaxf(zz.w * scale[kk + 3] + shift[kk + 3], 0.f);
        }
    }
    __syncthreads();
    const int c0 = cg * 8;
    float acc[8];
    #pragma unroll
    for (int c = 0; c < 8; ++c) acc[c] = bias[c0 + c];
    for (int kb = 0; kb < 64; ++kb) {
        const float a0 = at[(4 * kb + 0) * 16 + row];
        const float a1 = at[(4 * kb + 1) * 16 + row];
        const float a2 = at[(4 * kb + 2) * 16 + row];
        const float a3 = at[(4 * kb + 3) * 16 + row];
        #pragma unroll
        for (int c = 0; c < 8; ++c) {
            const float4 wv = *(const float4*)&W[(size_t)(c0 + c) * 256 + 4 * kb];
            acc[c] += a0 * wv.x + a1 * wv.y + a2 * wv.z + a3 * wv.w;
        }
    }
    {
        float* yr = y2 + (size_t)(rb + row) * 128 + c0;
        *(float4*)(yr)     = make_float4(acc[0], acc[1], acc[2], acc[3]);
        *(float4*)(yr + 4) = make_float4(acc[4], acc[5], acc[6], acc[7]);
    }
    #pragma unroll
    for (int c = 0; c < 8; ++c) {
        float s = acc[c], sq = acc[c] * acc[c];
        s += __shfl_xor(s, 1); sq += __shfl_xor(sq, 1);
        s += __shfl_xor(s, 2); sq += __shfl_xor(sq, 2);
        s += __shfl_xor(s, 4); sq += __shfl_xor(sq, 4);
        s += __shfl_xor(s, 8); sq += __shfl_xor(sq, 8);
        if (row == 0) { atomicAdd(&s2[c0 + c], s); atomicAdd(&q2[c0 + c], sq); }
    }
}

// ---------------------------------------------------------------------------
// fc3: y3 = relu(bn2(y2)) @ fc3_W^T + b  [4096,1], fused scalar stats
// ---------------------------------------------------------------------------
__global__ __launch_bounds__(256)
void k_fc3(const float* __restrict__ y2, const float* __restrict__ W3,
           const float* __restrict__ b3,
           const float* __restrict__ s2, const float* __restrict__ q2,
           const float* __restrict__ g2, const float* __restrict__ b2,
           float* __restrict__ y3, float* __restrict__ s3, float* __restrict__ q3)
{
    __shared__ float scale[128], shift[128], w3s[128];
    const int t = threadIdx.x;
    if (t < 128) {
        const float mu  = s2[t] * (1.f / BATCH);
        const float var = q2[t] * (1.f / BATCH) - mu * mu;
        const float sc  = g2[t] * rsq_fast(var + EPSF);
        scale[t] = sc;
        shift[t] = b2[t] - mu * sc;
        w3s[t]   = W3[t];
    }
    __syncthreads();
    const int r = blockIdx.x * 256 + t;
    float acc = b3[0];
    const float* yr = y2 + (size_t)r * 128;
    for (int kb = 0; kb < 32; ++kb) {
        const float4 v = *(const float4*)(yr + 4 * kb);
        const int kk = 4 * kb;
        acc += fmaxf(v.x * scale[kk + 0] + shift[kk + 0], 0.f) * w3s[kk + 0];
        acc += fmaxf(v.y * scale[kk + 1] + shift[kk + 1], 0.f) * w3s[kk + 1];
        acc += fmaxf(v.z * scale[kk + 2] + shift[kk + 2], 0.f) * w3s[kk + 2];
        acc += fmaxf(v.w * scale[kk + 3] + shift[kk + 3], 0.f) * w3s[kk + 3];
    }
    y3[r] = acc;
    float s = acc, sq = acc * acc;
    #pragma unroll
    for (int d = 1; d < 64; d <<= 1) { s += __shfl_xor(s, d); sq += __shfl_xor(sq, d); }
    if ((t & 63) == 0) { atomicAdd(&s3[0], s); atomicAdd(&q3[0], sq); }
}

// ---------------------------------------------------------------------------
// out = sigmoid(bn_out(y3))
// ---------------------------------------------------------------------------
__global__ __launch_bounds__(256)
void k_out(const float* __restrict__ y3,
           const float* __restrict__ s3, const float* __restrict__ q3,
           const float* __restrict__ g, const float* __restrict__ b,
           float* __restrict__ out)
{
    const int r = blockIdx.x * 256 + threadIdx.x;
    const float mu  = s3[0] * (1.f / BATCH);
    const float var = q3[0] * (1.f / BATCH) - mu * mu;
    const float sc  = g[0] * rsq_fast(var + EPSF);
    out[r] = sigm((y3[r] - mu) * sc + b[0]);
}

// ---------------------------------------------------------------------------
extern "C" void kernel_launch(void* const* d_in, const int* in_sizes, int n_in,
                              void* d_out, int out_size, void* d_ws, size_t ws_size,
                              hipStream_t stream)
{
    const float* x     = (const float*)d_in[0];
    const float* h_ext = (const float*)d_in[1];
    const float* c_ext = (const float*)d_in[2];
    const float* h_g0  = (const float*)d_in[3];
    const float* c_g0  = (const float*)d_in[4];
    const float* Wh    = (const float*)d_in[5];
    const float* bh    = (const float*)d_in[6];
    const float* Wc    = (const float*)d_in[7];
    const float* bc    = (const float*)d_in[8];
    const float* lnh_g = (const float*)d_in[9];
    const float* lnh_b = (const float*)d_in[10];
    const float* lnc_g = (const float*)d_in[11];
    const float* lnc_b = (const float*)d_in[12];
    const float* W_ih  = (const float*)d_in[13];
    const float* b_ih  = (const float*)d_in[14];
    const float* W_hh  = (const float*)d_in[15];
    const float* b_hh  = (const float*)d_in[16];
    const float* fc1_W = (const float*)d_in[17];
    const float* fc1_b = (const float*)d_in[18];
    const float* bn1_g = (const float*)d_in[19];
    const float* bn1_b = (const float*)d_in[20];
    const float* fc2_W = (const float*)d_in[21];
    const float* fc2_b = (const float*)d_in[22];
    const float* bn2_g = (const float*)d_in[23];
    const float* bn2_b = (const float*)d_in[24];
    const float* fc3_W = (const float*)d_in[25];
    const float* fc3_b = (const float*)d_in[26];
    const float* bno_g = (const float*)d_in[27];
    const float* bno_b = (const float*)d_in[28];

    // workspace layout
    short* whB_hi  = (short*)d_ws;                    // 81*8*12*512 = 3,981,312
    short* whB_lo  = whB_hi  + 3981312;
    short* wcB_hi  = whB_lo  + 3981312;
    short* wcB_lo  = wcB_hi  + 3981312;
    short* whhB_hi = wcB_lo  + 3981312;               // 81*32*4*512 = 5,308,416
    short* whhB_lo = whhB_hi + 5308416;
    float* hrow = (float*)(whhB_lo + 5308416);        // 4096*9*128
    float* crow = hrow + 4718592;
    float* z    = crow + 4718592;                     // 4096*256
    float* y1   = z    + 1048576;
    float* y2   = y1   + 1048576;
    float* y3   = y2   + 524288;
    float* st   = y3   + 4096;
    float* s1 = st;        float* q1 = s1 + 256;
    float* s2 = q1 + 256;  float* q2 = s2 + 128;
    float* s3 = q2 + 128;  float* q3 = s3 + 1;

    hipMemsetAsync(st, 0, 770 * sizeof(float), stream);
    hipLaunchKernelGGL(k_buildw, dim3(81 * 24), dim3(256), 0, stream,
                       Wh, Wc, W_hh, whB_hi, whB_lo, wcB_hi, wcB_lo, whhB_hi, whhB_lo);
    hipLaunchKernelGGL(k_lattice, dim3(NBLK), dim3(THREADS), 0, stream,
                       x, h_ext, c_ext, h_g0, c_g0,
                       whB_hi, whB_lo, wcB_hi, wcB_lo, whhB_hi, whhB_lo,
                       bh, bc, lnh_g, lnh_b, lnc_g, lnc_b, W_ih, b_ih, b_hh,
                       hrow, crow, z);
    hipLaunchKernelGGL(k_fc1, dim3(256), dim3(256), 0, stream, z, fc1_W, fc1_b, y1, s1, q1);
    hipLaunchKernelGGL(k_fc2, dim3(256), dim3(256), 0, stream,
                       y1, fc2_W, fc2_b, s1, q1, bn1_g, bn1_b, y2, s2, q2);
    hipLaunchKernelGGL(k_fc3, dim3(16), dim3(256), 0, stream,
                       y2, fc3_W, fc3_b, s2, q2, bn2_g, bn2_b, y3, s3, q3);
    hipLaunchKernelGGL(k_out, dim3(16), dim3(256), 0, stream,
                       y3, s3, q3, bno_g, bno_b, (float*)d_out);
}